// Round 3
// baseline (667.250 us; speedup 1.0000x reference)
//
#include <hip/hip_runtime.h>
#include <hip/hip_bf16.h>

typedef unsigned short u16;
typedef unsigned int u32;
typedef long long i64;

// ---------- bf16 helpers ----------
__device__ __forceinline__ float b2f(u16 u) {
    return __uint_as_float(((u32)u) << 16);
}
__device__ __forceinline__ u16 f2b(float f) {
    u32 u = __float_as_uint(f);
    u32 r = u + 0x7fffu + ((u >> 16) & 1u);   // round-to-nearest-even
    return (u16)(r >> 16);
}

// ---------- index storage detection ----------
// flags[0]: 1 = index tensors stored as int64, 0 = int32
__global__ void detect_k(const u32* __restrict__ ei, int* __restrict__ flags) {
    int lane = threadIdx.x;
    int oddZero = 0;
    for (int i = lane; i < 128; i += 64)
        if (ei[2 * i + 1] == 0) oddZero++;
#pragma unroll
    for (int o = 32; o > 0; o >>= 1) oddZero += __shfl_xor(oddZero, o, 64);
    if (lane == 0) flags[0] = (oddZero >= 126) ? 1 : 0;
}

// ---------- normalize index tensors to int32 ----------
__global__ __launch_bounds__(256) void cvtI_k(const void* __restrict__ ein,
                                              const void* __restrict__ rin,
                                              int* __restrict__ ei32,
                                              int* __restrict__ ri32,
                                              int E2, int E, const int* __restrict__ flags) {
    int i = blockIdx.x * 256 + threadIdx.x;
    int f = flags[0];
    if (i < E2) ei32[i] = f ? (int)((const i64*)ein)[i] : ((const int*)ein)[i];
    if (i < E)  ri32[i] = f ? (int)((const i64*)rin)[i] : ((const int*)rin)[i];
}

// ---------- f32 -> bf16 for x and relations ----------
__global__ __launch_bounds__(256) void cvtX_k(const float* __restrict__ xf,
                                              const float* __restrict__ relf,
                                              u16* __restrict__ x16,
                                              u16* __restrict__ rel16,
                                              int nx, int nr) {
    int i = blockIdx.x * 256 + threadIdx.x;
    if (i < nx) x16[i] = f2b(xf[i]);
    else {
        int j = i - nx;
        if (j < nr) rel16[j] = f2b(relf[j]);
    }
}

// ---------- copy relations (f32) to output tuple element 1, exact ----------
__global__ void copyR_k(const float* __restrict__ a, float* __restrict__ o, int n) {
    int i = blockIdx.x * blockDim.x + threadIdx.x;
    if (i < n) o[i] = a[i];
}

// ---------- CSR build ----------
__global__ void count_k(const int* __restrict__ dst, int* __restrict__ cnt, int E, int N) {
    int i = blockIdx.x * blockDim.x + threadIdx.x;
    if (i < E) {
        int d = dst[i];
        d = max(0, min(d, N - 1));
        atomicAdd(&cnt[d], 1);
    }
}

__global__ __launch_bounds__(1024) void scan_k(const int* __restrict__ cnt,
                                               int* __restrict__ rowptr, int n) {
    __shared__ int lds[1024];
    __shared__ int sbase;
    int t = threadIdx.x;
    if (t == 0) sbase = 0;
    __syncthreads();
    for (int start = 0; start < n; start += 1024) {
        int i = start + t;
        int v = (i < n) ? cnt[i] : 0;
        lds[t] = v;
        __syncthreads();
        for (int off = 1; off < 1024; off <<= 1) {
            int x = (t >= off) ? lds[t - off] : 0;
            __syncthreads();
            lds[t] += x;
            __syncthreads();
        }
        int incl = lds[t];
        int base = sbase;
        if (i < n) rowptr[i] = base + incl - v;   // exclusive
        __syncthreads();
        if (t == 1023) sbase = base + lds[1023];
        __syncthreads();
    }
    if (t == 0) rowptr[n] = sbase;
}

__global__ void scatter_k(const int* __restrict__ src, const int* __restrict__ dst,
                          const int* __restrict__ ridx, const int* __restrict__ rowptr,
                          int* __restrict__ cur, int* __restrict__ col_src,
                          int* __restrict__ col_rel, int E, int N, int R) {
    int i = blockIdx.x * blockDim.x + threadIdx.x;
    if (i < E) {
        int d = max(0, min(dst[i], N - 1));
        int s = max(0, min(src[i], N - 1));
        int r = max(0, min(ridx[i], R - 1));
        int pos = rowptr[d] + atomicAdd(&cur[d], 1);
        col_src[pos] = s;
        col_rel[pos] = r;
    }
}

// ---------- mean incoming edge_attr per node (shared by both layers) ----------
__global__ __launch_bounds__(256) void mean_k(const int* __restrict__ rowptr,
                                              const int* __restrict__ col_rel,
                                              const u16* __restrict__ rel,
                                              u16* __restrict__ ma, int N) {
    int node = blockIdx.x * 4 + (threadIdx.x >> 6);
    int lane = threadIdx.x & 63;
    if (node >= N) return;
    int beg = rowptr[node], end = rowptr[node + 1];
    float s = 0.f;
    for (int e = beg; e < end; ++e)
        s += b2f(rel[col_rel[e] * 64 + lane]);
    float d = (float)(end - beg);
    ma[node * 64 + lane] = f2b(s / fmaxf(d, 1.f));
}

// ---------- GEMM: rows x 64 @ 64 x 256 (W.T), W row cached in registers ----------
// blockIdx.y: 0 -> xl = X@Wl.T+bl, 1 -> xr = X@Wr.T+br, 2 -> me = MA@We.T, 3 -> re = REL@We.T
#define GROWS 64
__global__ __launch_bounds__(256) void gemm_k(
    const u16* __restrict__ Xin, const u16* __restrict__ MA, const u16* __restrict__ REL,
    const float* __restrict__ Wl, const float* __restrict__ bl,
    const float* __restrict__ Wr, const float* __restrict__ br,
    const float* __restrict__ We,
    u16* __restrict__ xl, u16* __restrict__ xr,
    u16* __restrict__ me, u16* __restrict__ re, int N, int R) {
    const u16* in;
    const float* W;
    const float* bias = nullptr;
    u16* out;
    int rows;
    switch (blockIdx.y) {
        case 0: in = Xin; W = Wl; bias = bl; out = xl; rows = N; break;
        case 1: in = Xin; W = Wr; bias = br; out = xr; rows = N; break;
        case 2: in = MA;  W = We; out = me; rows = N; break;
        default: in = REL; W = We; out = re; rows = R; break;
    }
    int row0 = blockIdx.x * GROWS;
    if (row0 >= rows) return;
    int t = threadIdx.x;   // output column 0..255

    // W row t (64 f32, contiguous 256B) -> registers
    float w[64];
    {
        const float4* wp = (const float4*)(W + (size_t)t * 64);
#pragma unroll
        for (int i = 0; i < 16; i++) {
            float4 q = wp[i];
            w[i * 4 + 0] = q.x;
            w[i * 4 + 1] = q.y;
            w[i * 4 + 2] = q.z;
            w[i * 4 + 3] = q.w;
        }
    }
    float bv = bias ? bias[t] : 0.f;

    __shared__ float xs[4][64];
    for (int rb = 0; rb < GROWS; rb += 4) {
        __syncthreads();
        {
            int rr = row0 + rb + (t >> 6);
            float v = 0.f;
            if (rr < rows) v = b2f(in[(size_t)rr * 64 + (t & 63)]);
            xs[t >> 6][t & 63] = v;
        }
        __syncthreads();
        float a0 = bv, a1 = bv, a2 = bv, a3 = bv;
#pragma unroll
        for (int k = 0; k < 64; k++) {
            float wk = w[k];
            a0 += xs[0][k] * wk;
            a1 += xs[1][k] * wk;
            a2 += xs[2][k] * wk;
            a3 += xs[3][k] * wk;
        }
        int r = row0 + rb;
        if (r + 0 < rows) out[(size_t)(r + 0) * 256 + t] = f2b(a0);
        if (r + 1 < rows) out[(size_t)(r + 1) * 256 + t] = f2b(a1);
        if (r + 2 < rows) out[(size_t)(r + 2) * 256 + t] = f2b(a2);
        if (r + 3 < rows) out[(size_t)(r + 3) * 256 + t] = f2b(a3);
    }
}

// ---------- fused edge phase: one wave per node, online softmax ----------
__global__ __launch_bounds__(256) void edge_agg(
    const int* __restrict__ rowptr, const int* __restrict__ col_src,
    const int* __restrict__ col_rel,
    const u16* __restrict__ xl, const u16* __restrict__ xr,
    const u16* __restrict__ me, const u16* __restrict__ re,
    const float* __restrict__ att, const float* __restrict__ bias,
    u16* __restrict__ outB, float* __restrict__ outF, int writeF32, int N) {
    int node = blockIdx.x * 4 + (threadIdx.x >> 6);
    int lane = threadIdx.x & 63;
    if (node >= N) return;

    float attv[4], xrv[4], xlv[4], mev[4];
#pragma unroll
    for (int h = 0; h < 4; h++) {
        attv[h] = att[h * 64 + lane];
        xrv[h]  = b2f(xr[(size_t)node * 256 + h * 64 + lane]);
        xlv[h]  = b2f(xl[(size_t)node * 256 + h * 64 + lane]);
        mev[h]  = b2f(me[(size_t)node * 256 + h * 64 + lane]);
    }

    // self-loop edge: m = xl[n] + xr[n] + me[n]
    float M[4], l[4], acc[4];
#pragma unroll
    for (int h = 0; h < 4; h++) {
        float m = xlv[h] + xrv[h] + mev[h];
        m = m > 0.f ? m : 0.2f * m;
        float tt = attv[h] * m;
#pragma unroll
        for (int o = 32; o > 0; o >>= 1) tt += __shfl_xor(tt, o, 64);
        M[h] = tt;      // running max starts at self alpha
        l[h] = 1.0f;    // exp(0)
        acc[h] = xlv[h];
    }

    int beg = rowptr[node], end = rowptr[node + 1];
    for (int e = beg; e < end; ++e) {
        int s = col_src[e], r = col_rel[e];
        float xls[4], alpha[4];
#pragma unroll
        for (int h = 0; h < 4; h++) {
            float xv = b2f(xl[(size_t)s * 256 + h * 64 + lane]);
            xls[h] = xv;
            float m = xv + xrv[h] + b2f(re[(size_t)r * 256 + h * 64 + lane]);
            m = m > 0.f ? m : 0.2f * m;
            float tt = attv[h] * m;
#pragma unroll
            for (int o = 32; o > 0; o >>= 1) tt += __shfl_xor(tt, o, 64);
            alpha[h] = tt;
        }
#pragma unroll
        for (int h = 0; h < 4; h++) {
            float Mn = fmaxf(M[h], alpha[h]);
            float corr = __expf(M[h] - Mn);
            float p = __expf(alpha[h] - Mn);
            l[h] = l[h] * corr + p;
            acc[h] = acc[h] * corr + p * xls[h];
            M[h] = Mn;
        }
    }

    float o = 0.f;
#pragma unroll
    for (int h = 0; h < 4; h++) o += acc[h] / l[h];
    o = o * 0.25f + bias[lane];                 // head mean + bias
    if (writeF32) outF[(size_t)node * 64 + lane] = o;
    else          outB[(size_t)node * 64 + lane] = f2b(o);
}

// ---------- launch ----------
extern "C" void kernel_launch(void* const* d_in, const int* in_sizes, int n_in,
                              void* d_out, int out_size, void* d_ws, size_t ws_size,
                              hipStream_t stream) {
    const float* xf   = (const float*)d_in[0];
    const float* relf = (const float*)d_in[2];

    const int N = in_sizes[0] / 64;   // 20000
    const int E = in_sizes[3];        // 320000
    const int R = in_sizes[2] / 64;   // 512

    const float* Wl[2] = {(const float*)d_in[4],  (const float*)d_in[11]};
    const float* bl[2] = {(const float*)d_in[5],  (const float*)d_in[12]};
    const float* Wr[2] = {(const float*)d_in[6],  (const float*)d_in[13]};
    const float* br[2] = {(const float*)d_in[7],  (const float*)d_in[14]};
    const float* We[2] = {(const float*)d_in[8],  (const float*)d_in[15]};
    const float* at[2] = {(const float*)d_in[9],  (const float*)d_in[16]};
    const float* bb[2] = {(const float*)d_in[10], (const float*)d_in[17]};

    // workspace carve
    char* p = (char*)d_ws;
    auto alloc = [&](size_t bytes) -> void* {
        void* r = (void*)p;
        p += (bytes + 255) & ~(size_t)255;
        return r;
    };
    int* flags   = (int*)alloc(256);
    int* ei32    = (int*)alloc((size_t)2 * E * 4);
    int* ri32    = (int*)alloc((size_t)E * 4);
    u16* x16     = (u16*)alloc((size_t)N * 64 * 2);
    u16* rel16   = (u16*)alloc((size_t)R * 64 * 2);
    int* cnt     = (int*)alloc((size_t)N * 4);
    int* rowptr  = (int*)alloc((size_t)(N + 1) * 4);
    int* col_src = (int*)alloc((size_t)E * 4);
    int* col_rel = (int*)alloc((size_t)E * 4);
    u16* ma  = (u16*)alloc((size_t)N * 64 * 2);
    u16* xlb = (u16*)alloc((size_t)N * 256 * 2);
    u16* xrb = (u16*)alloc((size_t)N * 256 * 2);
    u16* meb = (u16*)alloc((size_t)N * 256 * 2);
    u16* reb = (u16*)alloc((size_t)R * 256 * 2);
    u16* h0  = (u16*)alloc((size_t)N * 64 * 2);

    float* out = (float*)d_out;

    // 1. detect index storage (int64 vs int32); normalize to int32
    detect_k<<<1, 64, 0, stream>>>((const u32*)d_in[1], flags);
    cvtI_k<<<(2 * E + 255) / 256, 256, 0, stream>>>(d_in[1], d_in[3], ei32, ri32,
                                                    2 * E, E, flags);
    const int* src = ei32;
    const int* dst = ei32 + E;

    // 2. x, relations -> bf16 internal copies
    cvtX_k<<<(N * 64 + R * 64 + 255) / 256, 256, 0, stream>>>(xf, relf, x16, rel16,
                                                              N * 64, R * 64);

    // 3. CSR build over dst (identical both layers)
    hipMemsetAsync(cnt, 0, (size_t)N * 4, stream);
    count_k<<<(E + 255) / 256, 256, 0, stream>>>(dst, cnt, E, N);
    scan_k<<<1, 1024, 0, stream>>>(cnt, rowptr, N);
    hipMemsetAsync(cnt, 0, (size_t)N * 4, stream);
    scatter_k<<<(E + 255) / 256, 256, 0, stream>>>(src, dst, ri32, rowptr, cnt,
                                                   col_src, col_rel, E, N, R);
    mean_k<<<(N + 3) / 4, 256, 0, stream>>>(rowptr, col_rel, rel16, ma, N);
    copyR_k<<<(R * 64 + 255) / 256, 256, 0, stream>>>(relf, out + (size_t)N * 64, R * 64);

    // 4. two GATv2 layers
    dim3 ggrid((N + GROWS - 1) / GROWS, 4);
    for (int L = 0; L < 2; L++) {
        const u16* xin = (L == 0) ? x16 : h0;
        gemm_k<<<ggrid, 256, 0, stream>>>(xin, ma, rel16,
                                          Wl[L], bl[L], Wr[L], br[L], We[L],
                                          xlb, xrb, meb, reb, N, R);
        edge_agg<<<(N + 3) / 4, 256, 0, stream>>>(rowptr, col_src, col_rel,
                                                  xlb, xrb, meb, reb,
                                                  at[L], bb[L],
                                                  h0, out, (L == 1) ? 1 : 0, N);
    }
}

// Round 4
// 318.402 us; speedup vs baseline: 2.0956x; 2.0956x over previous
//
#include <hip/hip_runtime.h>
#include <hip/hip_bf16.h>

typedef unsigned short u16;
typedef unsigned int u32;
typedef long long i64;
typedef __attribute__((ext_vector_type(8))) short bf16x8;
typedef __attribute__((ext_vector_type(4))) float f32x4;

// ---------- bf16 helpers ----------
__device__ __forceinline__ float b2f(u16 u) {
    return __uint_as_float(((u32)u) << 16);
}
__device__ __forceinline__ u16 f2b(float f) {
    u32 u = __float_as_uint(f);
    u32 r = u + 0x7fffu + ((u >> 16) & 1u);   // round-to-nearest-even
    return (u16)(r >> 16);
}
// 4 consecutive bf16 -> 4 floats (8B load)
__device__ __forceinline__ void load4(const u16* p, float* v) {
    uint2 q = *(const uint2*)p;
    v[0] = __uint_as_float(q.x << 16);
    v[1] = __uint_as_float(q.x & 0xffff0000u);
    v[2] = __uint_as_float(q.y << 16);
    v[3] = __uint_as_float(q.y & 0xffff0000u);
}

// ---------- index storage detection ----------
__global__ void detect_k(const u32* __restrict__ ei, int* __restrict__ flags) {
    int lane = threadIdx.x;
    int oddZero = 0;
    for (int i = lane; i < 128; i += 64)
        if (ei[2 * i + 1] == 0) oddZero++;
#pragma unroll
    for (int o = 32; o > 0; o >>= 1) oddZero += __shfl_xor(oddZero, o, 64);
    if (lane == 0) flags[0] = (oddZero >= 126) ? 1 : 0;
}

// ---------- normalize indices to int32 + clamp + degree count ----------
__global__ __launch_bounds__(256) void cvtI_k(const void* __restrict__ ein,
                                              const void* __restrict__ rin,
                                              int* __restrict__ ei32,
                                              int* __restrict__ ri32,
                                              int E, const int* __restrict__ flags,
                                              int* __restrict__ cnt, int N, int R) {
    int i = blockIdx.x * 256 + threadIdx.x;
    int f = flags[0];
    if (i < 2 * E) {
        int x = f ? (int)((const i64*)ein)[i] : ((const int*)ein)[i];
        x = max(0, min(x, N - 1));
        ei32[i] = x;
        if (i >= E) atomicAdd(&cnt[x], 1);   // dst half -> in-degree
    }
    if (i < E) {
        int r = f ? (int)((const i64*)rin)[i] : ((const int*)rin)[i];
        ri32[i] = max(0, min(r, R - 1));
    }
}

// ---------- f32 -> bf16 conversion jobs ----------
struct CJob { const float* in; u16* out; int n; };
struct CJobs { CJob j[8]; };
__global__ __launch_bounds__(256) void cvt_k(CJobs jobs) {
    CJob job = jobs.j[blockIdx.y];
    int i = blockIdx.x * 256 + threadIdx.x;
    if (i < job.n) job.out[i] = f2b(job.in[i]);
}

// ---------- copy relations (f32) to output tuple element 1, exact ----------
__global__ void copyR_k(const float* __restrict__ a, float* __restrict__ o, int n) {
    int i = blockIdx.x * blockDim.x + threadIdx.x;
    if (i < n) o[i] = a[i];
}

// ---------- shuffle-based exclusive scan (single block, 1024 thr) ----------
__global__ __launch_bounds__(1024) void scan_k(const int* __restrict__ cnt,
                                               int* __restrict__ rowptr, int n) {
    __shared__ int wsum[16];
    __shared__ int sbase;
    int t = threadIdx.x, wave = t >> 6, lane = t & 63;
    if (t == 0) sbase = 0;
    __syncthreads();
    for (int start = 0; start < n; start += 1024) {
        int i = start + t;
        int v = (i < n) ? cnt[i] : 0;
        int x = v;
#pragma unroll
        for (int o = 1; o < 64; o <<= 1) {
            int y = __shfl_up(x, o, 64);
            if (lane >= o) x += y;
        }
        if (lane == 63) wsum[wave] = x;
        __syncthreads();
        if (wave == 0 && lane < 16) {
            int w = wsum[lane];
            int xw = w;
#pragma unroll
            for (int o = 1; o < 16; o <<= 1) {
                int y = __shfl_up(xw, o, 64);
                if (lane >= o) xw += y;
            }
            wsum[lane] = xw - w;   // exclusive wave offsets
        }
        __syncthreads();
        int base = sbase;
        __syncthreads();
        if (i < n) rowptr[i] = base + wsum[wave] + x - v;
        if (t == 1023) sbase = base + wsum[15] + x;
        __syncthreads();
    }
    if (t == 0) rowptr[n] = sbase;
}

__global__ void scatter_k(const int* __restrict__ src, const int* __restrict__ dst,
                          const int* __restrict__ ridx, const int* __restrict__ rowptr,
                          int* __restrict__ cur, int* __restrict__ col_src,
                          int* __restrict__ col_rel, int E) {
    int i = blockIdx.x * blockDim.x + threadIdx.x;
    if (i < E) {
        int d = dst[i];
        int pos = rowptr[d] + atomicAdd(&cur[d], 1);
        col_src[pos] = src[i];
        col_rel[pos] = ridx[i];
    }
}

// ---------- mean incoming edge_attr per node ----------
__global__ __launch_bounds__(256) void mean_k(const int* __restrict__ rowptr,
                                              const int* __restrict__ col_rel,
                                              const u16* __restrict__ rel,
                                              u16* __restrict__ ma, int N) {
    int node = blockIdx.x * 4 + (threadIdx.x >> 6);
    int lane = threadIdx.x & 63;
    if (node >= N) return;
    int beg = rowptr[node], end = rowptr[node + 1];
    float s = 0.f;
    for (int e = beg; e < end; ++e)
        s += b2f(rel[col_rel[e] * 64 + lane]);
    float d = (float)(end - beg);
    ma[node * 64 + lane] = f2b(s / fmaxf(d, 1.f));
}

// ---------- MFMA GEMM: OUT[rows x 256] = IN[rows x 64] @ W^T (+bias) ----------
// blockIdx.y: 0 -> Xin @ {Wl,Wr} -> xl,xr ; 1 -> MA @ We -> me ; 2 -> REL @ We -> re
// Verified layouts (m89/m91/m120): A: m=lane&15, k=quad*8+j ; B(from W[n][k]):
// n=lane&15, k=quad*8+j ; D: col=lane&15, row=quad*4+reg.
__global__ __launch_bounds__(256) void gemm_mfma(
    const u16* __restrict__ Xin, const u16* __restrict__ MA, const u16* __restrict__ REL,
    const u16* __restrict__ Wl16, const float* __restrict__ bl,
    const u16* __restrict__ Wr16, const float* __restrict__ br,
    const u16* __restrict__ We16,
    u16* __restrict__ xl, u16* __restrict__ xr,
    u16* __restrict__ me, u16* __restrict__ re, int N, int R) {
    int wave = threadIdx.x >> 6, lane = threadIdx.x & 63;
    int job = blockIdx.y;
    const u16* in;
    u16* out;
    int rows;
    if (job == 0)      { in = Xin; rows = N; out = xl; }
    else if (job == 1) { in = MA;  rows = N; out = me; }
    else               { in = REL; rows = R; out = re; }
    int row0 = blockIdx.x * 64 + wave * 16;
    if (row0 >= rows) return;

    int m = lane & 15, quad = lane >> 4;
    size_t row = (size_t)row0 + m;
    bf16x8 a0 = *(const bf16x8*)(in + row * 64 + quad * 8);
    bf16x8 a1 = *(const bf16x8*)(in + row * 64 + 32 + quad * 8);
    const u16* WA = (job == 0) ? Wl16 : We16;

    for (int ct = 0; ct < 16; ct++) {
        int n = ct * 16 + m;
        bf16x8 b0 = *(const bf16x8*)(WA + (size_t)n * 64 + quad * 8);
        bf16x8 b1 = *(const bf16x8*)(WA + (size_t)n * 64 + 32 + quad * 8);
        float bv = (job == 0) ? bl[n] : 0.f;
        f32x4 acc = {bv, bv, bv, bv};
        acc = __builtin_amdgcn_mfma_f32_16x16x32_bf16(a0, b0, acc, 0, 0, 0);
        acc = __builtin_amdgcn_mfma_f32_16x16x32_bf16(a1, b1, acc, 0, 0, 0);
#pragma unroll
        for (int i = 0; i < 4; i++)
            out[(size_t)(row0 + quad * 4 + i) * 256 + n] = f2b(acc[i]);
        if (job == 0) {
            bf16x8 c0 = *(const bf16x8*)(Wr16 + (size_t)n * 64 + quad * 8);
            bf16x8 c1 = *(const bf16x8*)(Wr16 + (size_t)n * 64 + 32 + quad * 8);
            float bv2 = br[n];
            f32x4 acc2 = {bv2, bv2, bv2, bv2};
            acc2 = __builtin_amdgcn_mfma_f32_16x16x32_bf16(a0, c0, acc2, 0, 0, 0);
            acc2 = __builtin_amdgcn_mfma_f32_16x16x32_bf16(a1, c1, acc2, 0, 0, 0);
#pragma unroll
            for (int i = 0; i < 4; i++)
                xr[(size_t)(row0 + quad * 4 + i) * 256 + n] = f2b(acc2[i]);
        }
    }
}

// ---------- fused edge phase: wave per node, head-split lanes, online softmax ----
// lane: head h = lane>>4, channels ci..ci+3 with ci = (lane&15)*4
__global__ __launch_bounds__(256) void edge_agg(
    const int* __restrict__ rowptr, const int* __restrict__ col_src,
    const int* __restrict__ col_rel,
    const u16* __restrict__ xl, const u16* __restrict__ xr,
    const u16* __restrict__ me, const u16* __restrict__ re,
    const float* __restrict__ att, const float* __restrict__ bias,
    u16* __restrict__ outB, float* __restrict__ outF, int writeF32, int N) {
    int node = blockIdx.x * 4 + (threadIdx.x >> 6);
    int lane = threadIdx.x & 63;
    if (node >= N) return;
    int h = lane >> 4;
    int ci = (lane & 15) * 4;
    int hoff = h * 64 + ci;
    size_t nb = (size_t)node * 256 + hoff;

    float av[4], xlv[4], xrv[4], mev[4];
    {
        float4 a4 = *(const float4*)(att + hoff);
        av[0] = a4.x; av[1] = a4.y; av[2] = a4.z; av[3] = a4.w;
    }
    load4(xl + nb, xlv);
    load4(xr + nb, xrv);
    load4(me + nb, mev);

    // self-loop: alpha from xl[n]+xr[n]+me[n]
    float t = 0.f, acc[4];
#pragma unroll
    for (int c = 0; c < 4; c++) {
        float mm = xlv[c] + xrv[c] + mev[c];
        mm = fmaxf(mm, 0.2f * mm);          // LeakyReLU(0.2)
        t = fmaf(av[c], mm, t);
        acc[c] = xlv[c];
    }
#pragma unroll
    for (int o = 1; o <= 8; o <<= 1) t += __shfl_xor(t, o, 64);
    float M = t, l = 1.0f;

    int e = rowptr[node], end = rowptr[node + 1];
    for (; e + 1 < end; e += 2) {
        int s0 = col_src[e], r0 = col_rel[e];
        int s1 = col_src[e + 1], r1 = col_rel[e + 1];
        float x0[4], v0[4], x1[4], v1[4];
        load4(xl + (size_t)s0 * 256 + hoff, x0);
        load4(re + (size_t)r0 * 256 + hoff, v0);
        load4(xl + (size_t)s1 * 256 + hoff, x1);
        load4(re + (size_t)r1 * 256 + hoff, v1);
        float t0 = 0.f, t1 = 0.f;
#pragma unroll
        for (int c = 0; c < 4; c++) {
            float m0 = x0[c] + xrv[c] + v0[c];
            m0 = fmaxf(m0, 0.2f * m0);
            t0 = fmaf(av[c], m0, t0);
            float m1 = x1[c] + xrv[c] + v1[c];
            m1 = fmaxf(m1, 0.2f * m1);
            t1 = fmaf(av[c], m1, t1);
        }
#pragma unroll
        for (int o = 1; o <= 8; o <<= 1) {
            t0 += __shfl_xor(t0, o, 64);
            t1 += __shfl_xor(t1, o, 64);
        }
        float Mn = fmaxf(M, fmaxf(t0, t1));
        float corr = __expf(M - Mn);
        float p0 = __expf(t0 - Mn);
        float p1 = __expf(t1 - Mn);
        l = l * corr + p0 + p1;
#pragma unroll
        for (int c = 0; c < 4; c++)
            acc[c] = acc[c] * corr + p0 * x0[c] + p1 * x1[c];
        M = Mn;
    }
    if (e < end) {
        int s0 = col_src[e], r0 = col_rel[e];
        float x0[4], v0[4];
        load4(xl + (size_t)s0 * 256 + hoff, x0);
        load4(re + (size_t)r0 * 256 + hoff, v0);
        float t0 = 0.f;
#pragma unroll
        for (int c = 0; c < 4; c++) {
            float m0 = x0[c] + xrv[c] + v0[c];
            m0 = fmaxf(m0, 0.2f * m0);
            t0 = fmaf(av[c], m0, t0);
        }
#pragma unroll
        for (int o = 1; o <= 8; o <<= 1) t0 += __shfl_xor(t0, o, 64);
        float Mn = fmaxf(M, t0);
        float corr = __expf(M - Mn);
        float p0 = __expf(t0 - Mn);
        l = l * corr + p0;
#pragma unroll
        for (int c = 0; c < 4; c++) acc[c] = acc[c] * corr + p0 * x0[c];
        M = Mn;
    }

    float o4[4];
#pragma unroll
    for (int c = 0; c < 4; c++) o4[c] = acc[c] / l;
    // sum across the 4 head groups (lanes differing in bits 4,5)
#pragma unroll
    for (int c = 0; c < 4; c++) {
        o4[c] += __shfl_xor(o4[c], 16, 64);
        o4[c] += __shfl_xor(o4[c], 32, 64);
    }
    if (lane < 16) {
        float4 b4 = *(const float4*)(bias + ci);
        float r0 = o4[0] * 0.25f + b4.x;
        float r1 = o4[1] * 0.25f + b4.y;
        float r2 = o4[2] * 0.25f + b4.z;
        float r3 = o4[3] * 0.25f + b4.w;
        if (writeF32) {
            float4 w = {r0, r1, r2, r3};
            *(float4*)(outF + (size_t)node * 64 + ci) = w;
        } else {
            ushort4 w;
            w.x = f2b(r0); w.y = f2b(r1); w.z = f2b(r2); w.w = f2b(r3);
            *(ushort4*)(outB + (size_t)node * 64 + ci) = w;
        }
    }
}

// ---------- launch ----------
extern "C" void kernel_launch(void* const* d_in, const int* in_sizes, int n_in,
                              void* d_out, int out_size, void* d_ws, size_t ws_size,
                              hipStream_t stream) {
    const float* xf   = (const float*)d_in[0];
    const float* relf = (const float*)d_in[2];

    const int N = in_sizes[0] / 64;   // 20000
    const int E = in_sizes[3];        // 320000
    const int R = in_sizes[2] / 64;   // 512

    const float* Wl[2] = {(const float*)d_in[4],  (const float*)d_in[11]};
    const float* bl[2] = {(const float*)d_in[5],  (const float*)d_in[12]};
    const float* Wr[2] = {(const float*)d_in[6],  (const float*)d_in[13]};
    const float* br[2] = {(const float*)d_in[7],  (const float*)d_in[14]};
    const float* We[2] = {(const float*)d_in[8],  (const float*)d_in[15]};
    const float* at[2] = {(const float*)d_in[9],  (const float*)d_in[16]};
    const float* bb[2] = {(const float*)d_in[10], (const float*)d_in[17]};

    // workspace carve
    char* p = (char*)d_ws;
    auto alloc = [&](size_t bytes) -> void* {
        void* r = (void*)p;
        p += (bytes + 255) & ~(size_t)255;
        return r;
    };
    int* flags   = (int*)alloc(256);
    int* ei32    = (int*)alloc((size_t)2 * E * 4);
    int* ri32    = (int*)alloc((size_t)E * 4);
    u16* x16     = (u16*)alloc((size_t)N * 64 * 2);
    u16* rel16   = (u16*)alloc((size_t)R * 64 * 2);
    u16* w16[6];
    for (int i = 0; i < 6; i++) w16[i] = (u16*)alloc((size_t)256 * 64 * 2);
    int* cnt     = (int*)alloc((size_t)N * 4);
    int* rowptr  = (int*)alloc((size_t)(N + 1) * 4);
    int* col_src = (int*)alloc((size_t)E * 4);
    int* col_rel = (int*)alloc((size_t)E * 4);
    u16* ma  = (u16*)alloc((size_t)N * 64 * 2);
    u16* xlb = (u16*)alloc((size_t)N * 256 * 2);
    u16* xrb = (u16*)alloc((size_t)N * 256 * 2);
    u16* meb = (u16*)alloc((size_t)N * 256 * 2);
    u16* reb = (u16*)alloc((size_t)R * 256 * 2);
    u16* h0  = (u16*)alloc((size_t)N * 64 * 2);

    float* out = (float*)d_out;

    // 1. index storage detect; normalize + clamp + in-degree count
    detect_k<<<1, 64, 0, stream>>>((const u32*)d_in[1], flags);
    hipMemsetAsync(cnt, 0, (size_t)N * 4, stream);
    cvtI_k<<<(2 * E + 255) / 256, 256, 0, stream>>>(d_in[1], d_in[3], ei32, ri32,
                                                    E, flags, cnt, N, R);
    const int* src = ei32;
    const int* dst = ei32 + E;

    // 2. f32 -> bf16: x, relations, 6 weight matrices
    CJobs jobs;
    jobs.j[0] = {xf,    x16,   N * 64};
    jobs.j[1] = {relf,  rel16, R * 64};
    jobs.j[2] = {Wl[0], w16[0], 256 * 64};
    jobs.j[3] = {Wr[0], w16[1], 256 * 64};
    jobs.j[4] = {We[0], w16[2], 256 * 64};
    jobs.j[5] = {Wl[1], w16[3], 256 * 64};
    jobs.j[6] = {Wr[1], w16[4], 256 * 64};
    jobs.j[7] = {We[1], w16[5], 256 * 64};
    dim3 cgrid((N * 64 + 255) / 256, 8);
    cvt_k<<<cgrid, 256, 0, stream>>>(jobs);

    // 3. CSR build
    scan_k<<<1, 1024, 0, stream>>>(cnt, rowptr, N);
    hipMemsetAsync(cnt, 0, (size_t)N * 4, stream);
    scatter_k<<<(E + 255) / 256, 256, 0, stream>>>(src, dst, ri32, rowptr, cnt,
                                                   col_src, col_rel, E);
    mean_k<<<(N + 3) / 4, 256, 0, stream>>>(rowptr, col_rel, rel16, ma, N);
    copyR_k<<<(R * 64 + 255) / 256, 256, 0, stream>>>(relf, out + (size_t)N * 64, R * 64);

    // 4. two GATv2 layers
    dim3 ggrid((N + 63) / 64, 3);
    for (int L = 0; L < 2; L++) {
        const u16* xin = (L == 0) ? x16 : h0;
        gemm_mfma<<<ggrid, 256, 0, stream>>>(xin, ma, rel16,
                                             w16[L * 3 + 0], bl[L],
                                             w16[L * 3 + 1], br[L],
                                             w16[L * 3 + 2],
                                             xlb, xrb, meb, reb, N, R);
        edge_agg<<<(N + 3) / 4, 256, 0, stream>>>(rowptr, col_src, col_rel,
                                                  xlb, xrb, meb, reb,
                                                  at[L], bb[L],
                                                  h0, out, (L == 1) ? 1 : 0, N);
    }
}

// Round 5
// 290.283 us; speedup vs baseline: 2.2986x; 1.0969x over previous
//
#include <hip/hip_runtime.h>
#include <hip/hip_bf16.h>

typedef unsigned short u16;
typedef unsigned int u32;
typedef long long i64;
typedef __attribute__((ext_vector_type(8))) short bf16x8;
typedef __attribute__((ext_vector_type(4))) float f32x4;

// ---------- bf16 helpers ----------
__device__ __forceinline__ float b2f(u16 u) {
    return __uint_as_float(((u32)u) << 16);
}
__device__ __forceinline__ u16 f2b(float f) {
    u32 u = __float_as_uint(f);
    u32 r = u + 0x7fffu + ((u >> 16) & 1u);   // round-to-nearest-even
    return (u16)(r >> 16);
}
// 4 consecutive bf16 -> 4 floats (8B load)
__device__ __forceinline__ void load4(const u16* p, float* v) {
    uint2 q = *(const uint2*)p;
    v[0] = __uint_as_float(q.x << 16);
    v[1] = __uint_as_float(q.x & 0xffff0000u);
    v[2] = __uint_as_float(q.y << 16);
    v[3] = __uint_as_float(q.y & 0xffff0000u);
}

// ---------- zero counters + index storage detection (one dispatch) ----------
__global__ __launch_bounds__(256) void zdetect_k(const u32* __restrict__ ei,
                                                 int* __restrict__ flags,
                                                 int* __restrict__ cnt,
                                                 int* __restrict__ cur, int N) {
    int i = blockIdx.x * 256 + threadIdx.x;
    if (i < N) { cnt[i] = 0; cur[i] = 0; }
    if (blockIdx.x == 0 && threadIdx.x < 64) {
        int lane = threadIdx.x;
        int oddZero = 0;
        for (int k = lane; k < 128; k += 64)
            if (ei[2 * k + 1] == 0) oddZero++;
#pragma unroll
        for (int o = 32; o > 0; o >>= 1) oddZero += __shfl_xor(oddZero, o, 64);
        if (lane == 0) flags[0] = (oddZero >= 126) ? 1 : 0;
    }
}

// ---------- normalize indices to int32 + clamp + degree count ----------
__global__ __launch_bounds__(256) void cvtI_k(const void* __restrict__ ein,
                                              const void* __restrict__ rin,
                                              int* __restrict__ ei32,
                                              int* __restrict__ ri32,
                                              int E, const int* __restrict__ flags,
                                              int* __restrict__ cnt, int N, int R) {
    int i = blockIdx.x * 256 + threadIdx.x;
    int f = flags[0];
    if (i < 2 * E) {
        int x = f ? (int)((const i64*)ein)[i] : ((const int*)ein)[i];
        x = max(0, min(x, N - 1));
        ei32[i] = x;
        if (i >= E) atomicAdd(&cnt[x], 1);   // dst half -> in-degree
    }
    if (i < E) {
        int r = f ? (int)((const i64*)rin)[i] : ((const int*)rin)[i];
        ri32[i] = max(0, min(r, R - 1));
    }
}

// ---------- f32 -> bf16 conversion jobs (4 elems/thread) ----------
struct CJob { const float* in; u16* out; int n4; };  // n4 = n/4
struct CJobs { CJob j[8]; };
__global__ __launch_bounds__(256) void cvt_k(CJobs jobs) {
    CJob job = jobs.j[blockIdx.y];
    int i = blockIdx.x * 256 + threadIdx.x;
    if (i < job.n4) {
        float4 v = ((const float4*)job.in)[i];
        ushort4 w;
        w.x = f2b(v.x); w.y = f2b(v.y); w.z = f2b(v.z); w.w = f2b(v.w);
        ((ushort4*)job.out)[i] = w;
    }
}

// ---------- copy relations (f32) to output tuple element 1, exact ----------
__global__ void copyR_k(const float4* __restrict__ a, float4* __restrict__ o, int n4) {
    int i = blockIdx.x * blockDim.x + threadIdx.x;
    if (i < n4) o[i] = a[i];
}

// ---------- shuffle-based exclusive scan (single block, 1024 thr) ----------
__global__ __launch_bounds__(1024) void scan_k(const int* __restrict__ cnt,
                                               int* __restrict__ rowptr, int n) {
    __shared__ int wsum[16];
    __shared__ int sbase;
    int t = threadIdx.x, wave = t >> 6, lane = t & 63;
    if (t == 0) sbase = 0;
    __syncthreads();
    for (int start = 0; start < n; start += 1024) {
        int i = start + t;
        int v = (i < n) ? cnt[i] : 0;
        int x = v;
#pragma unroll
        for (int o = 1; o < 64; o <<= 1) {
            int y = __shfl_up(x, o, 64);
            if (lane >= o) x += y;
        }
        if (lane == 63) wsum[wave] = x;
        __syncthreads();
        if (wave == 0 && lane < 16) {
            int w = wsum[lane];
            int xw = w;
#pragma unroll
            for (int o = 1; o < 16; o <<= 1) {
                int y = __shfl_up(xw, o, 64);
                if (lane >= o) xw += y;
            }
            wsum[lane] = xw - w;   // exclusive wave offsets
        }
        __syncthreads();
        int base = sbase;
        __syncthreads();
        if (i < n) rowptr[i] = base + wsum[wave] + x - v;
        if (t == 1023) sbase = base + wsum[15] + x;
        __syncthreads();
    }
    if (t == 0) rowptr[n] = sbase;
}

// ---------- scatter edges into CSR, packed (src, rel) ----------
__global__ void scatter_k(const int* __restrict__ src, const int* __restrict__ dst,
                          const int* __restrict__ ridx, const int* __restrict__ rowptr,
                          int* __restrict__ cur, int2* __restrict__ col, int E) {
    int i = blockIdx.x * blockDim.x + threadIdx.x;
    if (i < E) {
        int d = dst[i];
        int pos = rowptr[d] + atomicAdd(&cur[d], 1);
        col[pos] = make_int2(src[i], ridx[i]);
    }
}

// ---------- MFMA GEMM ----------
// blockIdx.y: 0 -> Xin @ {Wl,Wr} -> xl,xr (N rows) ; 1 -> REL @ We -> re (R rows)
// Layouts (verified): A: m=lane&15, k=quad*8+j ; B(from W[n][k]): n=lane&15,
// k=quad*8+j ; D: col=lane&15, row=quad*4+reg.
__global__ __launch_bounds__(256) void gemm_mfma(
    const u16* __restrict__ Xin, const u16* __restrict__ REL,
    const u16* __restrict__ Wl16, const float* __restrict__ bl,
    const u16* __restrict__ Wr16, const float* __restrict__ br,
    const u16* __restrict__ We16,
    u16* __restrict__ xl, u16* __restrict__ xr,
    u16* __restrict__ re, int N, int R) {
    int wave = threadIdx.x >> 6, lane = threadIdx.x & 63;
    int job = blockIdx.y;
    const u16* in = (job == 0) ? Xin : REL;
    int rows = (job == 0) ? N : R;
    u16* out = (job == 0) ? xl : re;
    int row0 = blockIdx.x * 64 + wave * 16;
    if (row0 >= rows) return;

    int m = lane & 15, quad = lane >> 4;
    size_t row = (size_t)row0 + m;
    bf16x8 a0 = *(const bf16x8*)(in + row * 64 + quad * 8);
    bf16x8 a1 = *(const bf16x8*)(in + row * 64 + 32 + quad * 8);
    const u16* WA = (job == 0) ? Wl16 : We16;

    for (int ct = 0; ct < 16; ct++) {
        int n = ct * 16 + m;
        bf16x8 b0 = *(const bf16x8*)(WA + (size_t)n * 64 + quad * 8);
        bf16x8 b1 = *(const bf16x8*)(WA + (size_t)n * 64 + 32 + quad * 8);
        float bv = (job == 0) ? bl[n] : 0.f;
        f32x4 acc = {bv, bv, bv, bv};
        acc = __builtin_amdgcn_mfma_f32_16x16x32_bf16(a0, b0, acc, 0, 0, 0);
        acc = __builtin_amdgcn_mfma_f32_16x16x32_bf16(a1, b1, acc, 0, 0, 0);
#pragma unroll
        for (int i = 0; i < 4; i++)
            out[(size_t)(row0 + quad * 4 + i) * 256 + n] = f2b(acc[i]);
        if (job == 0) {
            bf16x8 c0 = *(const bf16x8*)(Wr16 + (size_t)n * 64 + quad * 8);
            bf16x8 c1 = *(const bf16x8*)(Wr16 + (size_t)n * 64 + 32 + quad * 8);
            float bv2 = br[n];
            f32x4 acc2 = {bv2, bv2, bv2, bv2};
            acc2 = __builtin_amdgcn_mfma_f32_16x16x32_bf16(a0, c0, acc2, 0, 0, 0);
            acc2 = __builtin_amdgcn_mfma_f32_16x16x32_bf16(a1, c1, acc2, 0, 0, 0);
#pragma unroll
            for (int i = 0; i < 4; i++)
                xr[(size_t)(row0 + quad * 4 + i) * 256 + n] = f2b(acc2[i]);
        }
    }
}

// ---------- fused edge phase ----------
// wave per node; lane: head h = lane>>4, channels ci..ci+3, ci = (lane&15)*4.
// me (mean edge-attr projection) accumulated from re rows inside the loop;
// self-loop processed LAST (online softmax is order-independent).
__global__ __launch_bounds__(256) void edge_agg(
    const int* __restrict__ rowptr, const int2* __restrict__ col,
    const u16* __restrict__ xl, const u16* __restrict__ xr,
    const u16* __restrict__ re,
    const float* __restrict__ att, const float* __restrict__ bias,
    u16* __restrict__ outB, float* __restrict__ outF, int writeF32, int N) {
    int node = blockIdx.x * 4 + (threadIdx.x >> 6);
    int lane = threadIdx.x & 63;
    if (node >= N) return;
    int h = lane >> 4;
    int ci = (lane & 15) * 4;
    int hoff = h * 64 + ci;
    size_t nb = (size_t)node * 256 + hoff;

    float av[4], xlv[4], xrv[4];
    {
        float4 a4 = *(const float4*)(att + hoff);
        av[0] = a4.x; av[1] = a4.y; av[2] = a4.z; av[3] = a4.w;
    }
    load4(xl + nb, xlv);
    load4(xr + nb, xrv);

    float M = -3.0e38f, l = 0.f;
    float acc[4] = {0.f, 0.f, 0.f, 0.f};
    float mea[4] = {0.f, 0.f, 0.f, 0.f};

    int beg = rowptr[node], end = rowptr[node + 1];
    int e = beg;
    for (; e + 3 < end; e += 4) {
        int2 c0 = col[e], c1 = col[e + 1], c2 = col[e + 2], c3 = col[e + 3];
        float x0[4], x1[4], x2[4], x3[4], v0[4], v1[4], v2[4], v3[4];
        load4(xl + (size_t)c0.x * 256 + hoff, x0);
        load4(xl + (size_t)c1.x * 256 + hoff, x1);
        load4(xl + (size_t)c2.x * 256 + hoff, x2);
        load4(xl + (size_t)c3.x * 256 + hoff, x3);
        load4(re + (size_t)c0.y * 256 + hoff, v0);
        load4(re + (size_t)c1.y * 256 + hoff, v1);
        load4(re + (size_t)c2.y * 256 + hoff, v2);
        load4(re + (size_t)c3.y * 256 + hoff, v3);
        float t0 = 0.f, t1 = 0.f, t2 = 0.f, t3 = 0.f;
#pragma unroll
        for (int c = 0; c < 4; c++) {
            mea[c] += (v0[c] + v1[c]) + (v2[c] + v3[c]);
            float m0 = x0[c] + xrv[c] + v0[c]; m0 = fmaxf(m0, 0.2f * m0);
            float m1 = x1[c] + xrv[c] + v1[c]; m1 = fmaxf(m1, 0.2f * m1);
            float m2 = x2[c] + xrv[c] + v2[c]; m2 = fmaxf(m2, 0.2f * m2);
            float m3 = x3[c] + xrv[c] + v3[c]; m3 = fmaxf(m3, 0.2f * m3);
            t0 = fmaf(av[c], m0, t0);
            t1 = fmaf(av[c], m1, t1);
            t2 = fmaf(av[c], m2, t2);
            t3 = fmaf(av[c], m3, t3);
        }
#pragma unroll
        for (int o = 1; o <= 8; o <<= 1) {
            t0 += __shfl_xor(t0, o, 64);
            t1 += __shfl_xor(t1, o, 64);
            t2 += __shfl_xor(t2, o, 64);
            t3 += __shfl_xor(t3, o, 64);
        }
        float Mn = fmaxf(M, fmaxf(fmaxf(t0, t1), fmaxf(t2, t3)));
        float corr = __expf(M - Mn);
        float p0 = __expf(t0 - Mn), p1 = __expf(t1 - Mn);
        float p2 = __expf(t2 - Mn), p3 = __expf(t3 - Mn);
        l = l * corr + ((p0 + p1) + (p2 + p3));
#pragma unroll
        for (int c = 0; c < 4; c++)
            acc[c] = acc[c] * corr + (p0 * x0[c] + p1 * x1[c]) + (p2 * x2[c] + p3 * x3[c]);
        M = Mn;
    }
    for (; e < end; ++e) {
        int2 c0 = col[e];
        float x0[4], v0[4];
        load4(xl + (size_t)c0.x * 256 + hoff, x0);
        load4(re + (size_t)c0.y * 256 + hoff, v0);
        float t0 = 0.f;
#pragma unroll
        for (int c = 0; c < 4; c++) {
            mea[c] += v0[c];
            float m0 = x0[c] + xrv[c] + v0[c];
            m0 = fmaxf(m0, 0.2f * m0);
            t0 = fmaf(av[c], m0, t0);
        }
#pragma unroll
        for (int o = 1; o <= 8; o <<= 1) t0 += __shfl_xor(t0, o, 64);
        float Mn = fmaxf(M, t0);
        float corr = __expf(M - Mn);
        float p0 = __expf(t0 - Mn);
        l = l * corr + p0;
#pragma unroll
        for (int c = 0; c < 4; c++) acc[c] = acc[c] * corr + p0 * x0[c];
        M = Mn;
    }

    // self-loop: m = xl[n] + xr[n] + me[n],  me = mean of incoming re rows
    {
        float inv_d = 1.0f / fmaxf((float)(end - beg), 1.0f);
        float ts = 0.f;
#pragma unroll
        for (int c = 0; c < 4; c++) {
            float mm = xlv[c] + xrv[c] + mea[c] * inv_d;
            mm = fmaxf(mm, 0.2f * mm);
            ts = fmaf(av[c], mm, ts);
        }
#pragma unroll
        for (int o = 1; o <= 8; o <<= 1) ts += __shfl_xor(ts, o, 64);
        float Mn = fmaxf(M, ts);
        float corr = __expf(M - Mn);
        float ps = __expf(ts - Mn);
        l = l * corr + ps;
#pragma unroll
        for (int c = 0; c < 4; c++) acc[c] = acc[c] * corr + ps * xlv[c];
    }

    float o4[4];
    float invl = 1.0f / l;
#pragma unroll
    for (int c = 0; c < 4; c++) o4[c] = acc[c] * invl;
    // sum across the 4 head groups (lanes differing in bits 4,5)
#pragma unroll
    for (int c = 0; c < 4; c++) {
        o4[c] += __shfl_xor(o4[c], 16, 64);
        o4[c] += __shfl_xor(o4[c], 32, 64);
    }
    if (lane < 16) {
        float4 b4 = *(const float4*)(bias + ci);
        float r0 = o4[0] * 0.25f + b4.x;
        float r1 = o4[1] * 0.25f + b4.y;
        float r2 = o4[2] * 0.25f + b4.z;
        float r3 = o4[3] * 0.25f + b4.w;
        if (writeF32) {
            float4 w = {r0, r1, r2, r3};
            *(float4*)(outF + (size_t)node * 64 + ci) = w;
        } else {
            ushort4 w;
            w.x = f2b(r0); w.y = f2b(r1); w.z = f2b(r2); w.w = f2b(r3);
            *(ushort4*)(outB + (size_t)node * 64 + ci) = w;
        }
    }
}

// ---------- launch ----------
extern "C" void kernel_launch(void* const* d_in, const int* in_sizes, int n_in,
                              void* d_out, int out_size, void* d_ws, size_t ws_size,
                              hipStream_t stream) {
    const float* xf   = (const float*)d_in[0];
    const float* relf = (const float*)d_in[2];

    const int N = in_sizes[0] / 64;   // 20000
    const int E = in_sizes[3];        // 320000
    const int R = in_sizes[2] / 64;   // 512

    const float* Wl[2] = {(const float*)d_in[4],  (const float*)d_in[11]};
    const float* bl[2] = {(const float*)d_in[5],  (const float*)d_in[12]};
    const float* Wr[2] = {(const float*)d_in[6],  (const float*)d_in[13]};
    const float* br[2] = {(const float*)d_in[7],  (const float*)d_in[14]};
    const float* We[2] = {(const float*)d_in[8],  (const float*)d_in[15]};
    const float* at[2] = {(const float*)d_in[9],  (const float*)d_in[16]};
    const float* bb[2] = {(const float*)d_in[10], (const float*)d_in[17]};

    // workspace carve
    char* p = (char*)d_ws;
    auto alloc = [&](size_t bytes) -> void* {
        void* r = (void*)p;
        p += (bytes + 255) & ~(size_t)255;
        return r;
    };
    int* flags   = (int*)alloc(256);
    int* ei32    = (int*)alloc((size_t)2 * E * 4);
    int* ri32    = (int*)alloc((size_t)E * 4);
    u16* x16     = (u16*)alloc((size_t)N * 64 * 2);
    u16* rel16   = (u16*)alloc((size_t)R * 64 * 2);
    u16* w16[6];
    for (int i = 0; i < 6; i++) w16[i] = (u16*)alloc((size_t)256 * 64 * 2);
    int* cnt     = (int*)alloc((size_t)N * 4);
    int* cur     = (int*)alloc((size_t)N * 4);
    int* rowptr  = (int*)alloc((size_t)(N + 1) * 4);
    int2* col    = (int2*)alloc((size_t)E * 8);
    u16* xlb = (u16*)alloc((size_t)N * 256 * 2);
    u16* xrb = (u16*)alloc((size_t)N * 256 * 2);
    u16* reb = (u16*)alloc((size_t)R * 256 * 2);
    u16* h0  = (u16*)alloc((size_t)N * 64 * 2);

    float* out = (float*)d_out;

    // 1. zero counters + detect index storage
    zdetect_k<<<(N + 255) / 256, 256, 0, stream>>>((const u32*)d_in[1], flags,
                                                   cnt, cur, N);
    // 2. normalize + clamp indices, count in-degrees
    cvtI_k<<<(2 * E + 255) / 256, 256, 0, stream>>>(d_in[1], d_in[3], ei32, ri32,
                                                    E, flags, cnt, N, R);
    const int* src = ei32;
    const int* dst = ei32 + E;

    // 3. f32 -> bf16: x, relations, 6 weight matrices
    CJobs jobs;
    jobs.j[0] = {xf,    x16,    N * 16};
    jobs.j[1] = {relf,  rel16,  R * 16};
    jobs.j[2] = {Wl[0], w16[0], 256 * 16};
    jobs.j[3] = {Wr[0], w16[1], 256 * 16};
    jobs.j[4] = {We[0], w16[2], 256 * 16};
    jobs.j[5] = {Wl[1], w16[3], 256 * 16};
    jobs.j[6] = {Wr[1], w16[4], 256 * 16};
    jobs.j[7] = {We[1], w16[5], 256 * 16};
    dim3 cgrid((N * 16 + 255) / 256, 8);
    cvt_k<<<cgrid, 256, 0, stream>>>(jobs);

    // 4. CSR build + relations passthrough
    scan_k<<<1, 1024, 0, stream>>>(cnt, rowptr, N);
    scatter_k<<<(E + 255) / 256, 256, 0, stream>>>(src, dst, ri32, rowptr, cur,
                                                   col, E);
    copyR_k<<<(R * 16 + 255) / 256, 256, 0, stream>>>((const float4*)relf,
                                                      (float4*)(out + (size_t)N * 64),
                                                      R * 16);

    // 5. two GATv2 layers
    dim3 ggrid((N + 63) / 64, 2);
    for (int L = 0; L < 2; L++) {
        const u16* xin = (L == 0) ? x16 : h0;
        gemm_mfma<<<ggrid, 256, 0, stream>>>(xin, rel16,
                                             w16[L * 3 + 0], bl[L],
                                             w16[L * 3 + 1], br[L],
                                             w16[L * 3 + 2],
                                             xlb, xrb, reb, N, R);
        edge_agg<<<(N + 3) / 4, 256, 0, stream>>>(rowptr, col,
                                                  xlb, xrb, reb,
                                                  at[L], bb[L],
                                                  h0, out, (L == 1) ? 1 : 0, N);
    }
}